// Round 10
// baseline (7428.195 us; speedup 1.0000x reference)
//
#include <hip/hip_runtime.h>
#include <hip/hip_fp16.h>
#include <math.h>

#define HIDDEN 300
#define ATOM_FDIM 136
#define BOND_IN 148
#define MAX_NB 6
#define N_MOLS 4096
#define APM 32
#define N_ATOMS (N_MOLS*APM)
#define N_BONDS (2*N_ATOMS)

#define BK 16
#define BM 64
#define ASTR 68     // fp32-GEMM A-tile row stride (words)
#define BSTR 304    // fp32-GEMM B-tile row stride (words)

// Wt (split-bf16, transposed) geometry: [304 cols][320 k] per split
#define WT_C 304
#define WT_K 320

// mp_mfma geometry
#define MP_BM 32
#define MP_STR 328   // halves per A-tile row: 656B stride -> A-frag reads 2-way (free)

typedef unsigned short u16;
typedef short bf16x8 __attribute__((ext_vector_type(8)));
typedef float f32x4  __attribute__((ext_vector_type(4)));

// Fallback scratch if ws_size too small (same float count as the layout below).
__device__ float g_scratch[3ull * N_BONDS * HIDDEN + (size_t)N_MOLS * HIDDEN + WT_C * WT_K];

__device__ __forceinline__ u16 bf16_rne(float x) {
    unsigned u = __float_as_uint(x);
    unsigned r = (u + 0x7fffu + ((u >> 16) & 1u)) >> 16;
    return (u16)r;
}
__device__ __forceinline__ float bf16_f(u16 h) {
    return __uint_as_float(((unsigned)h) << 16);
}
__device__ __forceinline__ void st_h4(__half* p, float a, float b, float c, float d) {
    *(__half2*)(p)     = __floats2half2_rn(a, b);
    *(__half2*)(p + 2) = __floats2half2_rn(c, d);
}

// ---------------------------------------------------------------------------
// Prep: Wt_hi/Wt_lo[col][k] = split-bf16 of W_h[k][col], zero-padded to 304x320
// ---------------------------------------------------------------------------
__global__ __launch_bounds__(256)
void wt_prep(const float* __restrict__ W, u16* __restrict__ wt_hi, u16* __restrict__ wt_lo)
{
    const int i = blockIdx.x * 256 + threadIdx.x;
    if (i >= WT_C * WT_K) return;
    const int c = i / WT_K, k = i - c * WT_K;
    float w = (c < HIDDEN && k < HIDDEN) ? W[(size_t)k * HIDDEN + c] : 0.f;
    const u16 hi = bf16_rne(w);
    const u16 lo = bf16_rne(w - bf16_f(hi));
    wt_hi[i] = hi;
    wt_lo[i] = lo;
}

// ---------------------------------------------------------------------------
// Message-passing step via MFMA (split-bf16 math, fp16 storage):
//   out0 = fp16( relu(binput + gather6(msg) @ W_h) )
// Full A-tile staged in ONE pass (high memory-level parallelism: ~36
// independent 8B gathers/thread), ONE barrier, then all 10 MFMA K-steps
// barrier-free (A in LDS, B from L2-resident Wt).
// BM=32 rows, 512 threads / 8 waves: wave w -> m-tile (w&1), n-group (w>>1)
// covering 5 (or 4) n-tiles of 16. D map (m89): col=lane&15, row=(lane>>4)*4+j.
// ---------------------------------------------------------------------------
__global__ __launch_bounds__(512, 4)
void mp_mfma(const __half* __restrict__ msg,
             const int*   __restrict__ graph,
             const u16*   __restrict__ wt_hi,
             const u16*   __restrict__ wt_lo,
             const __half* __restrict__ binput,
             __half* __restrict__ out0)
{
    __shared__ u16 Ahi[MP_BM * MP_STR];   // 21 KB
    __shared__ u16 Alo[MP_BM * MP_STR];   // 21 KB
    __shared__ int gx[MP_BM * MAX_NB];

    const int tid  = threadIdx.x;
    const int row0 = blockIdx.x * MP_BM;

    if (tid < MP_BM * MAX_NB) gx[tid] = graph[(size_t)row0 * MAX_NB + tid];
    __syncthreads();

    // ---- stage: 16 threads/row; thread covers chunks kk = (tid&15)*8 + 128p
    const int sr = tid >> 4;            // row 0..31
    const int sc = (tid & 15) * 8;      // k-chunk base
    const int* sg = &gx[sr * MAX_NB];

    // zero-fill pad cols 304..327 (read by MFMA up to 319; must be defined)
    if ((tid & 15) < 3) {
        const int kp = 304 + (tid & 15) * 8;
        *(uint4*)&Ahi[sr * MP_STR + kp] = make_uint4(0, 0, 0, 0);
        *(uint4*)&Alo[sr * MP_STR + kp] = make_uint4(0, 0, 0, 0);
    }

#pragma unroll
    for (int p = 0; p < 3; ++p) {
        const int kk = sc + 128 * p;
        if (kk < 304) {
            float s[8];
#pragma unroll
            for (int e = 0; e < 8; ++e) s[e] = 0.f;
            const bool hi_ok = (kk + 4 < HIDDEN);   // skip 300..303 sub-chunk (kk==296)
#pragma unroll
            for (int j = 0; j < MAX_NB; ++j) {
                const __half* rp = msg + (size_t)sg[j] * HIDDEN + kk;   // 8B-aligned
                const uint2 q0 = *(const uint2*)rp;
                const uint2 q1 = hi_ok ? *(const uint2*)(rp + 4) : make_uint2(0u, 0u);
                const float2 a0 = __half22float2(*(const __half2*)&q0.x);
                const float2 a1 = __half22float2(*(const __half2*)&q0.y);
                const float2 a2 = __half22float2(*(const __half2*)&q1.x);
                const float2 a3 = __half22float2(*(const __half2*)&q1.y);
                s[0] += a0.x; s[1] += a0.y; s[2] += a1.x; s[3] += a1.y;
                s[4] += a2.x; s[5] += a2.y; s[6] += a3.x; s[7] += a3.y;
            }
            u16 h[8], e[8];
#pragma unroll
            for (int q = 0; q < 8; ++q) {
                h[q] = bf16_rne(s[q]);
                e[q] = bf16_rne(s[q] - bf16_f(h[q]));
            }
            uint4 ph, pl;
            ph.x = (unsigned)h[0] | ((unsigned)h[1] << 16);
            ph.y = (unsigned)h[2] | ((unsigned)h[3] << 16);
            ph.z = (unsigned)h[4] | ((unsigned)h[5] << 16);
            ph.w = (unsigned)h[6] | ((unsigned)h[7] << 16);
            pl.x = (unsigned)e[0] | ((unsigned)e[1] << 16);
            pl.y = (unsigned)e[2] | ((unsigned)e[3] << 16);
            pl.z = (unsigned)e[4] | ((unsigned)e[5] << 16);
            pl.w = (unsigned)e[6] | ((unsigned)e[7] << 16);
            *(uint4*)&Ahi[sr * MP_STR + kk] = ph;
            *(uint4*)&Alo[sr * MP_STR + kk] = pl;
        }
    }
    __syncthreads();

    // ---- MFMA phase (barrier-free)
    const int w  = tid >> 6;
    const int l  = tid & 63;
    const int g  = l >> 4;              // k-chunk 0..3 within 32-step
    const int mt = w & 1;               // m-tile
    const int ng = w >> 1;              // n-group 0..3
    const int nbase  = ng * 5;
    const int ntiles = (ng < 3) ? 5 : 4;
    const int mr = mt * 16 + (l & 15);  // A-frag row

    f32x4 acc[5];
#pragma unroll
    for (int t = 0; t < 5; ++t) acc[t] = (f32x4){0.f, 0.f, 0.f, 0.f};

    for (int k0 = 0; k0 < HIDDEN; k0 += 32) {
        const int kb = k0 + 8 * g;
        const bf16x8 ahi = *(const bf16x8*)&Ahi[mr * MP_STR + kb];
        const bf16x8 alo = *(const bf16x8*)&Alo[mr * MP_STR + kb];
#pragma unroll
        for (int t = 0; t < 5; ++t) {
            if (t < ntiles) {
                const int cn = 16 * (nbase + t) + (l & 15);
                const bf16x8 bhi = *(const bf16x8*)&wt_hi[(size_t)cn * WT_K + kb];
                const bf16x8 blo = *(const bf16x8*)&wt_lo[(size_t)cn * WT_K + kb];
                acc[t] = __builtin_amdgcn_mfma_f32_16x16x32_bf16(ahi, bhi, acc[t], 0, 0, 0);
                acc[t] = __builtin_amdgcn_mfma_f32_16x16x32_bf16(ahi, blo, acc[t], 0, 0, 0);
                acc[t] = __builtin_amdgcn_mfma_f32_16x16x32_bf16(alo, bhi, acc[t], 0, 0, 0);
            }
        }
    }

    // ---- epilogue: D[row=4g+j][col=l&15] per tile; binput nt-load (streamed)
    const u16* bin_u = (const u16*)binput;
#pragma unroll
    for (int t = 0; t < 5; ++t) {
        if (t < ntiles) {
            const int col = 16 * (nbase + t) + (l & 15);
            if (col < HIDDEN) {
#pragma unroll
                for (int j = 0; j < 4; ++j) {
                    const size_t off = (size_t)(row0 + mt * 16 + 4 * g + j) * HIDDEN + col;
                    const u16 raw = __builtin_nontemporal_load(bin_u + off);
                    const float bi = __half2float(__ushort_as_half(raw));
                    out0[off] = __float2half(fmaxf(bi + acc[t][j], 0.f));
                }
            }
        }
    }
}

// ---------------------------------------------------------------------------
// fp32 fused GEMM family (R6/R7/R8-proven skeleton). 512 threads, BM=64, BK=16.
//  MODE 0: A=fbonds[lda]            -> out0=fp16(A@W), out1=fp16(relu(A@W))
//  MODE 2: A=concat(fatoms, gather from fp16 msg) -> out0=relu(A@W + bias)
//  MODE 3: A dense [lda]            -> out0=A@W
//  MODE 4: A dense (P_all)          -> out0[mol]=(hsum+sum_rows relu(A@W+bias))/32
// ---------------------------------------------------------------------------
template<int MODE>
__global__ __launch_bounds__(512)
void gemm_fused(const float* __restrict__ Adense, int lda,
                const void*  __restrict__ msgv,
                const int*   __restrict__ graph,
                const float* __restrict__ W,
                const float* __restrict__ bias,
                const float* __restrict__ hsum,
                float* __restrict__ out0,
                float* __restrict__ out1,
                int K)
{
    __shared__ float As[BK * ASTR];
    __shared__ float Bs[BK * BSTR];
    __shared__ int   gx[BM * MAX_NB];

    const int tid  = threadIdx.x;
    const int wave = tid >> 6;
    const int lane = tid & 63;
    const int row0 = blockIdx.x * BM;
    const int c0   = 4 * lane;
    const bool has4 = (lane < HIDDEN - 256);
    const int  c4   = has4 ? (256 + lane) : 256;

    if (MODE == 2) {
        if (tid < BM * MAX_NB) gx[tid] = graph[(size_t)row0 * MAX_NB + tid];
        __syncthreads();
    }

    float acc[8][5];
#pragma unroll
    for (int r = 0; r < 8; ++r)
#pragma unroll
        for (int c = 0; c < 5; ++c) acc[r][c] = 0.f;

    const int nk = (K + BK - 1) / BK;
    for (int kt = 0; kt < nk; ++kt) {
        const int k0 = kt * BK;
        for (int i = tid; i < BK * 300; i += 512) {
            const int kk = i / 300;
            const int col = i - kk * 300;
            const int k = k0 + kk;
            Bs[kk * BSTR + col] = (k < K) ? W[(size_t)k * HIDDEN + col] : 0.f;
        }
        for (int i = tid; i < BK * BM; i += 512) {
            const int r  = i >> 4;
            const int kk = i & 15;
            const int k  = k0 + kk;
            float v = 0.f;
            if (MODE == 0 || MODE == 3 || MODE == 4) {
                if (k < K) v = Adense[(size_t)(row0 + r) * lda + k];
            } else { // MODE 2: concat(fatoms[0:136], gather6 fp16 msg [136:436])
                if (k < ATOM_FDIM) {
                    v = Adense[(size_t)(row0 + r) * lda + k];
                } else if (k < K) {
                    const int kc = k - ATOM_FDIM;
                    const __half* mh = (const __half*)msgv;
#pragma unroll
                    for (int j = 0; j < MAX_NB; ++j)
                        v += __half2float(mh[(size_t)gx[r * MAX_NB + j] * HIDDEN + kc]);
                }
            }
            As[kk * ASTR + r] = v;
        }
        __syncthreads();
#pragma unroll
        for (int kk = 0; kk < BK; ++kk) {
            const float4 bq = *(const float4*)&Bs[kk * BSTR + c0];
            const float  b4 = Bs[kk * BSTR + c4];
            const float4 a0 = *(const float4*)&As[kk * ASTR + wave * 8];
            const float4 a1 = *(const float4*)&As[kk * ASTR + wave * 8 + 4];
            const float ar8[8] = {a0.x, a0.y, a0.z, a0.w, a1.x, a1.y, a1.z, a1.w};
#pragma unroll
            for (int r = 0; r < 8; ++r) {
                acc[r][0] = fmaf(ar8[r], bq.x, acc[r][0]);
                acc[r][1] = fmaf(ar8[r], bq.y, acc[r][1]);
                acc[r][2] = fmaf(ar8[r], bq.z, acc[r][2]);
                acc[r][3] = fmaf(ar8[r], bq.w, acc[r][3]);
                acc[r][4] = fmaf(ar8[r], b4,   acc[r][4]);
            }
        }
        __syncthreads();
    }

    if (MODE == 4) {
        const float4 bqv = *(const float4*)&bias[c0];
        const float  b4v = bias[c4];
        float s0 = 0, s1 = 0, s2 = 0, s3 = 0, s4 = 0;
#pragma unroll
        for (int r = 0; r < 8; ++r) {
            s0 += fmaxf(acc[r][0] + bqv.x, 0.f);
            s1 += fmaxf(acc[r][1] + bqv.y, 0.f);
            s2 += fmaxf(acc[r][2] + bqv.z, 0.f);
            s3 += fmaxf(acc[r][3] + bqv.w, 0.f);
            s4 += fmaxf(acc[r][4] + b4v,   0.f);
        }
        float* wsum = Bs;
        *(float4*)&wsum[wave * BSTR + c0] = make_float4(s0, s1, s2, s3);
        if (has4) wsum[wave * BSTR + c4] = s4;
        __syncthreads();
        const int m0 = blockIdx.x * 2;
        for (int t = tid; t < 2 * HIDDEN; t += 512) {
            const int m = t / HIDDEN, col = t - m * HIDDEN;
            const float v = wsum[(4 * m + 0) * BSTR + col] + wsum[(4 * m + 1) * BSTR + col]
                          + wsum[(4 * m + 2) * BSTR + col] + wsum[(4 * m + 3) * BSTR + col]
                          + hsum[(size_t)(m0 + m) * HIDDEN + col];
            out0[(size_t)(m0 + m) * HIDDEN + col] = v * (1.f / 32.f);
        }
        return;
    }

#pragma unroll
    for (int r = 0; r < 8; ++r) {
        const size_t off = (size_t)(row0 + wave * 8 + r) * HIDDEN;
        float4 v = make_float4(acc[r][0], acc[r][1], acc[r][2], acc[r][3]);
        float v4 = acc[r][4];
        if (MODE == 0) {
            __half* o0 = (__half*)out0;
            __half* o1 = (__half*)out1;
            st_h4(&o0[off + c0], v.x, v.y, v.z, v.w);
            if (has4) o0[off + c4] = __float2half(v4);
            st_h4(&o1[off + c0], fmaxf(v.x,0.f), fmaxf(v.y,0.f), fmaxf(v.z,0.f), fmaxf(v.w,0.f));
            if (has4) o1[off + c4] = __float2half(fmaxf(v4, 0.f));
        } else if (MODE == 2) {
            const float4 bb = *(const float4*)&bias[c0];
            float4 rv = make_float4(fmaxf(v.x+bb.x,0.f), fmaxf(v.y+bb.y,0.f),
                                    fmaxf(v.z+bb.z,0.f), fmaxf(v.w+bb.w,0.f));
            *(float4*)&out0[off + c0] = rv;
            if (has4) out0[off + c4] = fmaxf(v4 + bias[c4], 0.f);
        } else { // MODE 3
            *(float4*)&out0[off + c0] = v;
            if (has4) out0[off + c4] = v4;
        }
    }
}

// ---------------------------------------------------------------------------
// Per-molecule middle stage (R6/R7/R8-proven): logits, softmax, P=att@h, hsum.
// ---------------------------------------------------------------------------
#define HSTR 320

__device__ __forceinline__ int hsw(int a, int c4u) {
    return a * HSTR + ((c4u ^ (a & 7)) << 2);
}

__global__ __launch_bounds__(512)
void attn_mid(const float* __restrict__ atom_h,
              const float* __restrict__ q_all,
              float* __restrict__ P_all,
              float* __restrict__ hsum)
{
    __shared__ float hs[APM * HSTR];
    __shared__ float qs[APM * HIDDEN];
    __shared__ float att[APM][33];

    const int tid  = threadIdx.x;
    const int wave = tid >> 6;
    const int lane = tid & 63;
    const int mol  = blockIdx.x;
    const float* hb = atom_h + (size_t)mol * APM * HIDDEN;
    const float* qb = q_all  + (size_t)mol * APM * HIDDEN;

    for (int j = tid; j < APM * 75; j += 512) {
        const int a = j / 75, c4u = j - a * 75;
        *(float4*)&hs[hsw(a, c4u)] = *(const float4*)&hb[(size_t)a * HIDDEN + 4 * c4u];
    }
    for (int j = tid; j < APM * 75; j += 512)
        *(float4*)&qs[4 * j] = *(const float4*)&qb[4 * j];
    __syncthreads();

    {
        const int a = tid >> 5, b = tid & 31;
        float s0 = 0.f, s1 = 0.f;
        for (int t = 0; t < 75; ++t) {
            const float4 hv = *(const float4*)&hs[hsw(b, t)];
            const float4 q0 = *(const float4*)&qs[a * HIDDEN + 4 * t];
            const float4 q1 = *(const float4*)&qs[(a + 16) * HIDDEN + 4 * t];
            s0 = fmaf(q0.x, hv.x, fmaf(q0.y, hv.y, fmaf(q0.z, hv.z, fmaf(q0.w, hv.w, s0))));
            s1 = fmaf(q1.x, hv.x, fmaf(q1.y, hv.y, fmaf(q1.z, hv.z, fmaf(q1.w, hv.w, s1))));
        }
        att[a][b] = s0;
        att[a + 16][b] = s1;
    }
    __syncthreads();

    if (tid < APM) {
        float m = -3.4e38f;
#pragma unroll 4
        for (int b = 0; b < APM; ++b) m = fmaxf(m, att[tid][b]);
        float s = 0.f;
#pragma unroll 4
        for (int b = 0; b < APM; ++b) { const float e = __expf(att[tid][b] - m); att[tid][b] = e; s += e; }
        const float inv = 1.f / s;
#pragma unroll 4
        for (int b = 0; b < APM; ++b) att[tid][b] *= inv;
    }
    __syncthreads();

    {
        const int r0 = wave * 4;
        const int c0 = 4 * lane;
        const bool has4 = (lane < 44);
        const int c4u = 64 + (lane >> 2), c4r = lane & 3;
        float4 p[4];
        float  p4[4];
#pragma unroll
        for (int r = 0; r < 4; ++r) { p[r] = make_float4(0,0,0,0); p4[r] = 0.f; }
#pragma unroll 4
        for (int b = 0; b < APM; ++b) {
            const float4 hv = *(const float4*)&hs[hsw(b, lane)];
            const float  h4 = hs[hsw(b, c4u) + c4r];
#pragma unroll
            for (int r = 0; r < 4; ++r) {
                const float av = att[r0 + r][b];
                p[r].x = fmaf(av, hv.x, p[r].x);
                p[r].y = fmaf(av, hv.y, p[r].y);
                p[r].z = fmaf(av, hv.z, p[r].z);
                p[r].w = fmaf(av, hv.w, p[r].w);
                p4[r]  = fmaf(av, h4,   p4[r]);
            }
        }
#pragma unroll
        for (int r = 0; r < 4; ++r) {
            const size_t off = ((size_t)mol * APM + r0 + r) * HIDDEN;
            *(float4*)&P_all[off + c0] = p[r];
            if (has4) P_all[off + 256 + lane] = p4[r];
        }
    }

    if (tid < HIDDEN) {
        const int c4u = tid >> 2, cr = tid & 3;
        float s = 0.f;
#pragma unroll 4
        for (int a = 0; a < APM; ++a) s += hs[hsw(a, c4u) + cr];
        hsum[(size_t)mol * HIDDEN + tid] = s;
    }
}

// ---------------------------------------------------------------------------
extern "C" void kernel_launch(void* const* d_in, const int* in_sizes, int n_in,
                              void* d_out, int out_size, void* d_ws, size_t ws_size,
                              hipStream_t stream)
{
    const float* fatoms = (const float*)d_in[0];
    const float* fbonds = (const float*)d_in[1];
    const int*   agraph = (const int*)d_in[2];
    const int*   bgraph = (const int*)d_in[3];
    const float* W_i    = (const float*)d_in[4];
    const float* W_h    = (const float*)d_in[5];
    const float* W_o    = (const float*)d_in[6];
    const float* b_o    = (const float*)d_in[7];
    const float* W_a    = (const float*)d_in[8];
    const float* W_b    = (const float*)d_in[9];
    const float* b_b    = (const float*)d_in[10];
    float* out = (float*)d_out;

    const size_t WB = (size_t)N_BONDS * HIDDEN;   // 78,643,200
    const size_t WA = (size_t)N_ATOMS * HIDDEN;   // 39,321,600
    // float-unit layout: binput_h(WB/2) | msgA(WB/2) | msgB(WB/2) |
    //                    atom_h(WA) | q_all(WA) | P_all(WA) | hsum | wt
    const size_t need = (3 * WB / 2 + 3 * WA + (size_t)N_MOLS * HIDDEN + WT_C * WT_K) * sizeof(float);
    float* base;
    if (ws_size >= need) {
        base = (float*)d_ws;
    } else {
        void* p = nullptr;
        (void)hipGetSymbolAddress(&p, HIP_SYMBOL(g_scratch));
        base = (float*)p;
    }
    __half* binput_h = (__half*)base;
    __half* msgA     = (__half*)(base + WB / 2);
    __half* msgB     = (__half*)(base + WB);
    float*  atom_h   = base + 3 * WB / 2;
    float*  q_all    = atom_h + WA;
    float*  P_all    = q_all + WA;
    float*  hsum     = P_all + WA;
    u16*    wt_hi    = (u16*)(hsum + (size_t)N_MOLS * HIDDEN);
    u16*    wt_lo    = wt_hi + WT_C * WT_K;

    const dim3 blk(512);

    // split/transpose W_h once per call
    wt_prep<<<(WT_C * WT_K + 255) / 256, dim3(256), 0, stream>>>(W_h, wt_hi, wt_lo);

    // binput_h = fp16(fbonds @ W_i) ; msgA = fp16(relu(...))
    gemm_fused<0><<<N_BONDS / BM, blk, 0, stream>>>(
        fbonds, BOND_IN, nullptr, nullptr, W_i, nullptr, nullptr,
        (float*)binput_h, (float*)msgA, BOND_IN);

    // 5 message-passing iterations — MFMA path, fp16 storage, 1-barrier staging
    const __half* cur = msgA;
    __half* nxt = msgB;
    for (int it = 0; it < 5; ++it) {
        mp_mfma<<<N_BONDS / MP_BM, blk, 0, stream>>>(
            cur, bgraph, wt_hi, wt_lo, binput_h, nxt);
        __half* t = nxt; nxt = (__half*)cur; cur = t;
    }
    // final message in cur

    // atom_h = relu(concat(fatoms, gather6(fp16 msg)) @ W_o + b_o)
    gemm_fused<2><<<N_ATOMS / BM, blk, 0, stream>>>(
        fatoms, ATOM_FDIM, (const void*)cur, agraph, W_o, b_o, nullptr,
        atom_h, nullptr, ATOM_FDIM + HIDDEN);

    // q_all = atom_h @ W_a
    gemm_fused<3><<<N_ATOMS / BM, blk, 0, stream>>>(
        atom_h, HIDDEN, nullptr, nullptr, W_a, nullptr, nullptr,
        q_all, nullptr, HIDDEN);

    // per-molecule: logits, softmax, P = att@h, hsum
    attn_mid<<<N_MOLS, dim3(512), 0, stream>>>(atom_h, q_all, P_all, hsum);

    // out[mol] = (hsum + sum_rows relu(P @ W_b + b_b)) / 32
    gemm_fused<4><<<N_ATOMS / BM, blk, 0, stream>>>(
        P_all, HIDDEN, nullptr, nullptr, W_b, b_b, hsum,
        out, nullptr, HIDDEN);
}

// Round 12
// 7187.508 us; speedup vs baseline: 1.0335x; 1.0335x over previous
//
#include <hip/hip_runtime.h>
#include <hip/hip_fp16.h>
#include <math.h>

#define HIDDEN 300
#define ATOM_FDIM 136
#define BOND_IN 148
#define MAX_NB 6
#define N_MOLS 4096
#define APM 32
#define N_ATOMS (N_MOLS*APM)
#define N_BONDS (2*N_ATOMS)

#define BK 16
#define BM 64
#define ASTR 68     // fp32-GEMM A-tile row stride (words)
#define BSTR 304    // fp32-GEMM B-tile row stride (words)

// Wt (split-bf16, transposed) geometry: [304 cols][320 k] per split
#define WT_C 304
#define WT_K 320

typedef unsigned short u16;
typedef short bf16x8 __attribute__((ext_vector_type(8)));
typedef float f32x4  __attribute__((ext_vector_type(4)));

// Fallback scratch if ws_size too small (same float count as the layout below).
__device__ float g_scratch[3ull * N_BONDS * HIDDEN + (size_t)N_MOLS * HIDDEN + WT_C * WT_K];

__device__ __forceinline__ u16 bf16_rne(float x) {
    unsigned u = __float_as_uint(x);
    unsigned r = (u + 0x7fffu + ((u >> 16) & 1u)) >> 16;
    return (u16)r;
}
__device__ __forceinline__ float bf16_f(u16 h) {
    return __uint_as_float(((unsigned)h) << 16);
}
__device__ __forceinline__ void st_h4(__half* p, float a, float b, float c, float d) {
    *(__half2*)(p)     = __floats2half2_rn(a, b);
    *(__half2*)(p + 2) = __floats2half2_rn(c, d);
}

// ---------------------------------------------------------------------------
// Prep: Wt_hi/Wt_lo[col][k] = split-bf16 of W_h[k][col], zero-padded to 304x320
// ---------------------------------------------------------------------------
__global__ __launch_bounds__(256)
void wt_prep(const float* __restrict__ W, u16* __restrict__ wt_hi, u16* __restrict__ wt_lo)
{
    const int i = blockIdx.x * 256 + threadIdx.x;
    if (i >= WT_C * WT_K) return;
    const int c = i / WT_K, k = i - c * WT_K;
    float w = (c < HIDDEN && k < HIDDEN) ? W[(size_t)k * HIDDEN + c] : 0.f;
    const u16 hi = bf16_rne(w);
    const u16 lo = bf16_rne(w - bf16_f(hi));
    wt_hi[i] = hi;
    wt_lo[i] = lo;
}

// ---------------------------------------------------------------------------
// Message-passing step via MFMA (split-bf16 math, fp16 storage):
//   out0 = fp16( relu(binput + gather6(msg) @ W_h) )
// R8-proven per-K-step structure (BM=64, 2 barriers/step) + T14 async-STAGE
// split: next K-step's 6 gather loads are ISSUED (into regs) right after the
// stage barrier, BEFORE the MFMA phase — gather latency hides under MFMA+B
// loads, keeping memory requests in flight continuously (fixes R10's bursty
// phase-synchronized demand). binput read nontemporal (frees L3 for msg).
// D map (m89): col = lane&15, row = (lane>>4)*4 + j.
// ---------------------------------------------------------------------------
__global__ __launch_bounds__(512, 4)
void mp_mfma(const __half* __restrict__ msg,
             const int*   __restrict__ graph,
             const u16*   __restrict__ wt_hi,
             const u16*   __restrict__ wt_lo,
             const __half* __restrict__ binput,
             __half* __restrict__ out0)
{
    __shared__ u16 Ahi[64 * 40];   // row stride 40 u16 = 80B (16B-aligned)
    __shared__ u16 Alo[64 * 40];
    __shared__ int gx[64 * MAX_NB];

    const int tid  = threadIdx.x;
    const int row0 = blockIdx.x * 64;

    if (tid < 64 * MAX_NB) gx[tid] = graph[(size_t)row0 * MAX_NB + tid];
    __syncthreads();

    const int w  = tid >> 6;          // wave 0..7
    const int l  = tid & 63;
    const int g  = l >> 4;            // k-chunk 0..3
    const int mr = (w & 3) * 16 + (l & 15);      // A-frag row (block-local)
    const int tbase = (w >> 2) ? 10 : 0;         // n-tile group
    const int ntile = (w >> 2) ? 9 : 10;

    const int sr = tid >> 3;          // stage row 0..63
    const int sk = (tid & 7) * 4;     // stage k-offset 0..28
    // per-thread gather row base pointers (fixed across K-steps)
    const __half* rp0; const __half* rp1; const __half* rp2;
    const __half* rp3; const __half* rp4; const __half* rp5;
    {
        const int* sg = &gx[sr * MAX_NB];
        rp0 = msg + (size_t)sg[0] * HIDDEN + sk;
        rp1 = msg + (size_t)sg[1] * HIDDEN + sk;
        rp2 = msg + (size_t)sg[2] * HIDDEN + sk;
        rp3 = msg + (size_t)sg[3] * HIDDEN + sk;
        rp4 = msg + (size_t)sg[4] * HIDDEN + sk;
        rp5 = msg + (size_t)sg[5] * HIDDEN + sk;
    }
    // (reads may run up to 19 halves past a row's 300: that's the next row's
    //  finite fp16 data (or finite 0xAA poison), and Wt is zero for k>=300,
    //  so those products vanish — proven-safe in R7/R8.)

    f32x4 acc[10];
#pragma unroll
    for (int t = 0; t < 10; ++t) acc[t] = (f32x4){0.f, 0.f, 0.f, 0.f};

    // prologue: issue K-step 0 gathers
    uint2 pre[6];
    pre[0] = *(const uint2*)rp0;  pre[1] = *(const uint2*)rp1;
    pre[2] = *(const uint2*)rp2;  pre[3] = *(const uint2*)rp3;
    pre[4] = *(const uint2*)rp4;  pre[5] = *(const uint2*)rp5;

    for (int k0 = 0; k0 < HIDDEN; k0 += 32) {
        // ---- commit: fp32 sum of prefetched gathers -> split bf16 -> LDS
        float s0 = 0.f, s1 = 0.f, s2 = 0.f, s3 = 0.f;
#pragma unroll
        for (int j = 0; j < 6; ++j) {
            const float2 a0 = __half22float2(*(const __half2*)&pre[j].x);
            const float2 a1 = __half22float2(*(const __half2*)&pre[j].y);
            s0 += a0.x; s1 += a0.y; s2 += a1.x; s3 += a1.y;
        }
        const u16 h0 = bf16_rne(s0), h1 = bf16_rne(s1), h2 = bf16_rne(s2), h3 = bf16_rne(s3);
        const u16 e0 = bf16_rne(s0 - bf16_f(h0)), e1 = bf16_rne(s1 - bf16_f(h1));
        const u16 e2 = bf16_rne(s2 - bf16_f(h2)), e3 = bf16_rne(s3 - bf16_f(h3));
        uint2 ph, pl;
        ph.x = (unsigned)h0 | ((unsigned)h1 << 16);
        ph.y = (unsigned)h2 | ((unsigned)h3 << 16);
        pl.x = (unsigned)e0 | ((unsigned)e1 << 16);
        pl.y = (unsigned)e2 | ((unsigned)e3 << 16);
        *(uint2*)&Ahi[sr * 40 + sk] = ph;
        *(uint2*)&Alo[sr * 40 + sk] = pl;
        __syncthreads();

        // ---- T14 issue-early: next K-step's gathers fly during MFMA below
        const int kn = k0 + 32;
        if (kn < HIDDEN) {
            pre[0] = *(const uint2*)(rp0 + kn);  pre[1] = *(const uint2*)(rp1 + kn);
            pre[2] = *(const uint2*)(rp2 + kn);  pre[3] = *(const uint2*)(rp3 + kn);
            pre[4] = *(const uint2*)(rp4 + kn);  pre[5] = *(const uint2*)(rp5 + kn);
        }

        // ---- MFMA phase: A frags from LDS, B frags from L2-resident Wt
        const bf16x8 ahi = *(const bf16x8*)&Ahi[mr * 40 + 8 * g];
        const bf16x8 alo = *(const bf16x8*)&Alo[mr * 40 + 8 * g];
        const int kb = k0 + 8 * g;
#pragma unroll
        for (int t = 0; t < 10; ++t) {
            if (t < ntile) {
                const int cn = 16 * (tbase + t) + (l & 15);
                const bf16x8 bhi = *(const bf16x8*)&wt_hi[(size_t)cn * WT_K + kb];
                const bf16x8 blo = *(const bf16x8*)&wt_lo[(size_t)cn * WT_K + kb];
                acc[t] = __builtin_amdgcn_mfma_f32_16x16x32_bf16(ahi, bhi, acc[t], 0, 0, 0);
                acc[t] = __builtin_amdgcn_mfma_f32_16x16x32_bf16(ahi, blo, acc[t], 0, 0, 0);
                acc[t] = __builtin_amdgcn_mfma_f32_16x16x32_bf16(alo, bhi, acc[t], 0, 0, 0);
            }
        }
        __syncthreads();
    }

    // ---- epilogue: D[row=(l>>4)*4+j][col=l&15]; binput nontemporal (streamed)
    const u16* bin_u = (const u16*)binput;
#pragma unroll
    for (int t = 0; t < 10; ++t) {
        if (t < ntile) {
            const int col = 16 * (tbase + t) + (l & 15);
            if (col < HIDDEN) {
#pragma unroll
                for (int j = 0; j < 4; ++j) {
                    const size_t off = (size_t)(row0 + (w & 3) * 16 + 4 * g + j) * HIDDEN + col;
                    const u16 raw = __builtin_nontemporal_load(bin_u + off);
                    const float bi = __half2float(__ushort_as_half(raw));
                    out0[off] = __float2half(fmaxf(bi + acc[t][j], 0.f));
                }
            }
        }
    }
}

// ---------------------------------------------------------------------------
// fp32 fused GEMM family (R6/R7/R8-proven skeleton). 512 threads, BM=64, BK=16.
//  MODE 0: A=fbonds[lda]            -> out0=fp16(A@W), out1=fp16(relu(A@W))
//  MODE 2: A=concat(fatoms, gather from fp16 msg) -> out0=relu(A@W + bias)
//  MODE 3: A dense [lda]            -> out0=A@W
//  MODE 4: A dense (P_all)          -> out0[mol]=(hsum+sum_rows relu(A@W+bias))/32
// ---------------------------------------------------------------------------
template<int MODE>
__global__ __launch_bounds__(512)
void gemm_fused(const float* __restrict__ Adense, int lda,
                const void*  __restrict__ msgv,
                const int*   __restrict__ graph,
                const float* __restrict__ W,
                const float* __restrict__ bias,
                const float* __restrict__ hsum,
                float* __restrict__ out0,
                float* __restrict__ out1,
                int K)
{
    __shared__ float As[BK * ASTR];
    __shared__ float Bs[BK * BSTR];
    __shared__ int   gx[BM * MAX_NB];

    const int tid  = threadIdx.x;
    const int wave = tid >> 6;
    const int lane = tid & 63;
    const int row0 = blockIdx.x * BM;
    const int c0   = 4 * lane;
    const bool has4 = (lane < HIDDEN - 256);
    const int  c4   = has4 ? (256 + lane) : 256;

    if (MODE == 2) {
        if (tid < BM * MAX_NB) gx[tid] = graph[(size_t)row0 * MAX_NB + tid];
        __syncthreads();
    }

    float acc[8][5];
#pragma unroll
    for (int r = 0; r < 8; ++r)
#pragma unroll
        for (int c = 0; c < 5; ++c) acc[r][c] = 0.f;

    const int nk = (K + BK - 1) / BK;
    for (int kt = 0; kt < nk; ++kt) {
        const int k0 = kt * BK;
        for (int i = tid; i < BK * 300; i += 512) {
            const int kk = i / 300;
            const int col = i - kk * 300;
            const int k = k0 + kk;
            Bs[kk * BSTR + col] = (k < K) ? W[(size_t)k * HIDDEN + col] : 0.f;
        }
        for (int i = tid; i < BK * BM; i += 512) {
            const int r  = i >> 4;
            const int kk = i & 15;
            const int k  = k0 + kk;
            float v = 0.f;
            if (MODE == 0 || MODE == 3 || MODE == 4) {
                if (k < K) v = Adense[(size_t)(row0 + r) * lda + k];
            } else { // MODE 2: concat(fatoms[0:136], gather6 fp16 msg [136:436])
                if (k < ATOM_FDIM) {
                    v = Adense[(size_t)(row0 + r) * lda + k];
                } else if (k < K) {
                    const int kc = k - ATOM_FDIM;
                    const __half* mh = (const __half*)msgv;
#pragma unroll
                    for (int j = 0; j < MAX_NB; ++j)
                        v += __half2float(mh[(size_t)gx[r * MAX_NB + j] * HIDDEN + kc]);
                }
            }
            As[kk * ASTR + r] = v;
        }
        __syncthreads();
#pragma unroll
        for (int kk = 0; kk < BK; ++kk) {
            const float4 bq = *(const float4*)&Bs[kk * BSTR + c0];
            const float  b4 = Bs[kk * BSTR + c4];
            const float4 a0 = *(const float4*)&As[kk * ASTR + wave * 8];
            const float4 a1 = *(const float4*)&As[kk * ASTR + wave * 8 + 4];
            const float ar8[8] = {a0.x, a0.y, a0.z, a0.w, a1.x, a1.y, a1.z, a1.w};
#pragma unroll
            for (int r = 0; r < 8; ++r) {
                acc[r][0] = fmaf(ar8[r], bq.x, acc[r][0]);
                acc[r][1] = fmaf(ar8[r], bq.y, acc[r][1]);
                acc[r][2] = fmaf(ar8[r], bq.z, acc[r][2]);
                acc[r][3] = fmaf(ar8[r], bq.w, acc[r][3]);
                acc[r][4] = fmaf(ar8[r], b4,   acc[r][4]);
            }
        }
        __syncthreads();
    }

    if (MODE == 4) {
        const float4 bqv = *(const float4*)&bias[c0];
        const float  b4v = bias[c4];
        float s0 = 0, s1 = 0, s2 = 0, s3 = 0, s4 = 0;
#pragma unroll
        for (int r = 0; r < 8; ++r) {
            s0 += fmaxf(acc[r][0] + bqv.x, 0.f);
            s1 += fmaxf(acc[r][1] + bqv.y, 0.f);
            s2 += fmaxf(acc[r][2] + bqv.z, 0.f);
            s3 += fmaxf(acc[r][3] + bqv.w, 0.f);
            s4 += fmaxf(acc[r][4] + b4v,   0.f);
        }
        float* wsum = Bs;
        *(float4*)&wsum[wave * BSTR + c0] = make_float4(s0, s1, s2, s3);
        if (has4) wsum[wave * BSTR + c4] = s4;
        __syncthreads();
        const int m0 = blockIdx.x * 2;
        for (int t = tid; t < 2 * HIDDEN; t += 512) {
            const int m = t / HIDDEN, col = t - m * HIDDEN;
            const float v = wsum[(4 * m + 0) * BSTR + col] + wsum[(4 * m + 1) * BSTR + col]
                          + wsum[(4 * m + 2) * BSTR + col] + wsum[(4 * m + 3) * BSTR + col]
                          + hsum[(size_t)(m0 + m) * HIDDEN + col];
            out0[(size_t)(m0 + m) * HIDDEN + col] = v * (1.f / 32.f);
        }
        return;
    }

#pragma unroll
    for (int r = 0; r < 8; ++r) {
        const size_t off = (size_t)(row0 + wave * 8 + r) * HIDDEN;
        float4 v = make_float4(acc[r][0], acc[r][1], acc[r][2], acc[r][3]);
        float v4 = acc[r][4];
        if (MODE == 0) {
            __half* o0 = (__half*)out0;
            __half* o1 = (__half*)out1;
            st_h4(&o0[off + c0], v.x, v.y, v.z, v.w);
            if (has4) o0[off + c4] = __float2half(v4);
            st_h4(&o1[off + c0], fmaxf(v.x,0.f), fmaxf(v.y,0.f), fmaxf(v.z,0.f), fmaxf(v.w,0.f));
            if (has4) o1[off + c4] = __float2half(fmaxf(v4, 0.f));
        } else if (MODE == 2) {
            const float4 bb = *(const float4*)&bias[c0];
            float4 rv = make_float4(fmaxf(v.x+bb.x,0.f), fmaxf(v.y+bb.y,0.f),
                                    fmaxf(v.z+bb.z,0.f), fmaxf(v.w+bb.w,0.f));
            *(float4*)&out0[off + c0] = rv;
            if (has4) out0[off + c4] = fmaxf(v4 + bias[c4], 0.f);
        } else { // MODE 3
            *(float4*)&out0[off + c0] = v;
            if (has4) out0[off + c4] = v4;
        }
    }
}

// ---------------------------------------------------------------------------
// Per-molecule middle stage (R6/R7/R8-proven): logits, softmax, P=att@h, hsum.
// ---------------------------------------------------------------------------
#define HSTR 320

__device__ __forceinline__ int hsw(int a, int c4u) {
    return a * HSTR + ((c4u ^ (a & 7)) << 2);
}

__global__ __launch_bounds__(512)
void attn_mid(const float* __restrict__ atom_h,
              const float* __restrict__ q_all,
              float* __restrict__ P_all,
              float* __restrict__ hsum)
{
    __shared__ float hs[APM * HSTR];
    __shared__ float qs[APM * HIDDEN];
    __shared__ float att[APM][33];

    const int tid  = threadIdx.x;
    const int wave = tid >> 6;
    const int lane = tid & 63;
    const int mol  = blockIdx.x;
    const float* hb = atom_h + (size_t)mol * APM * HIDDEN;
    const float* qb = q_all  + (size_t)mol * APM * HIDDEN;

    for (int j = tid; j < APM * 75; j += 512) {
        const int a = j / 75, c4u = j - a * 75;
        *(float4*)&hs[hsw(a, c4u)] = *(const float4*)&hb[(size_t)a * HIDDEN + 4 * c4u];
    }
    for (int j = tid; j < APM * 75; j += 512)
        *(float4*)&qs[4 * j] = *(const float4*)&qb[4 * j];
    __syncthreads();

    {
        const int a = tid >> 5, b = tid & 31;
        float s0 = 0.f, s1 = 0.f;
        for (int t = 0; t < 75; ++t) {
            const float4 hv = *(const float4*)&hs[hsw(b, t)];
            const float4 q0 = *(const float4*)&qs[a * HIDDEN + 4 * t];
            const float4 q1 = *(const float4*)&qs[(a + 16) * HIDDEN + 4 * t];
            s0 = fmaf(q0.x, hv.x, fmaf(q0.y, hv.y, fmaf(q0.z, hv.z, fmaf(q0.w, hv.w, s0))));
            s1 = fmaf(q1.x, hv.x, fmaf(q1.y, hv.y, fmaf(q1.z, hv.z, fmaf(q1.w, hv.w, s1))));
        }
        att[a][b] = s0;
        att[a + 16][b] = s1;
    }
    __syncthreads();

    if (tid < APM) {
        float m = -3.4e38f;
#pragma unroll 4
        for (int b = 0; b < APM; ++b) m = fmaxf(m, att[tid][b]);
        float s = 0.f;
#pragma unroll 4
        for (int b = 0; b < APM; ++b) { const float e = __expf(att[tid][b] - m); att[tid][b] = e; s += e; }
        const float inv = 1.f / s;
#pragma unroll 4
        for (int b = 0; b < APM; ++b) att[tid][b] *= inv;
    }
    __syncthreads();

    {
        const int r0 = wave * 4;
        const int c0 = 4 * lane;
        const bool has4 = (lane < 44);
        const int c4u = 64 + (lane >> 2), c4r = lane & 3;
        float4 p[4];
        float  p4[4];
#pragma unroll
        for (int r = 0; r < 4; ++r) { p[r] = make_float4(0,0,0,0); p4[r] = 0.f; }
#pragma unroll 4
        for (int b = 0; b < APM; ++b) {
            const float4 hv = *(const float4*)&hs[hsw(b, lane)];
            const float  h4 = hs[hsw(b, c4u) + c4r];
#pragma unroll
            for (int r = 0; r < 4; ++r) {
                const float av = att[r0 + r][b];
                p[r].x = fmaf(av, hv.x, p[r].x);
                p[r].y = fmaf(av, hv.y, p[r].y);
                p[r].z = fmaf(av, hv.z, p[r].z);
                p[r].w = fmaf(av, hv.w, p[r].w);
                p4[r]  = fmaf(av, h4,   p4[r]);
            }
        }
#pragma unroll
        for (int r = 0; r < 4; ++r) {
            const size_t off = ((size_t)mol * APM + r0 + r) * HIDDEN;
            *(float4*)&P_all[off + c0] = p[r];
            if (has4) P_all[off + 256 + lane] = p4[r];
        }
    }

    if (tid < HIDDEN) {
        const int c4u = tid >> 2, cr = tid & 3;
        float s = 0.f;
#pragma unroll 4
        for (int a = 0; a < APM; ++a) s += hs[hsw(a, c4u) + cr];
        hsum[(size_t)mol * HIDDEN + tid] = s;
    }
}

// ---------------------------------------------------------------------------
extern "C" void kernel_launch(void* const* d_in, const int* in_sizes, int n_in,
                              void* d_out, int out_size, void* d_ws, size_t ws_size,
                              hipStream_t stream)
{
    const float* fatoms = (const float*)d_in[0];
    const float* fbonds = (const float*)d_in[1];
    const int*   agraph = (const int*)d_in[2];
    const int*   bgraph = (const int*)d_in[3];
    const float* W_i    = (const float*)d_in[4];
    const float* W_h    = (const float*)d_in[5];
    const float* W_o    = (const float*)d_in[6];
    const float* b_o    = (const float*)d_in[7];
    const float* W_a    = (const float*)d_in[8];
    const float* W_b    = (const float*)d_in[9];
    const float* b_b    = (const float*)d_in[10];
    float* out = (float*)d_out;

    const size_t WB = (size_t)N_BONDS * HIDDEN;   // 78,643,200
    const size_t WA = (size_t)N_ATOMS * HIDDEN;   // 39,321,600
    // float-unit layout: binput_h(WB/2) | msgA(WB/2) | msgB(WB/2) |
    //                    atom_h(WA) | q_all(WA) | P_all(WA) | hsum | wt
    const size_t need = (3 * WB / 2 + 3 * WA + (size_t)N_MOLS * HIDDEN + WT_C * WT_K) * sizeof(float);
    float* base;
    if (ws_size >= need) {
        base = (float*)d_ws;
    } else {
        void* p = nullptr;
        (void)hipGetSymbolAddress(&p, HIP_SYMBOL(g_scratch));
        base = (float*)p;
    }
    __half* binput_h = (__half*)base;
    __half* msgA     = (__half*)(base + WB / 2);
    __half* msgB     = (__half*)(base + WB);
    float*  atom_h   = base + 3 * WB / 2;
    float*  q_all    = atom_h + WA;
    float*  P_all    = q_all + WA;
    float*  hsum     = P_all + WA;
    u16*    wt_hi    = (u16*)(hsum + (size_t)N_MOLS * HIDDEN);
    u16*    wt_lo    = wt_hi + WT_C * WT_K;

    const dim3 blk(512);

    // split/transpose W_h once per call
    wt_prep<<<(WT_C * WT_K + 255) / 256, dim3(256), 0, stream>>>(W_h, wt_hi, wt_lo);

    // binput_h = fp16(fbonds @ W_i) ; msgA = fp16(relu(...))
    gemm_fused<0><<<N_BONDS / BM, blk, 0, stream>>>(
        fbonds, BOND_IN, nullptr, nullptr, W_i, nullptr, nullptr,
        (float*)binput_h, (float*)msgA, BOND_IN);

    // 5 message-passing iterations — MFMA path, fp16 storage, T14 overlap
    const __half* cur = msgA;
    __half* nxt = msgB;
    for (int it = 0; it < 5; ++it) {
        mp_mfma<<<N_BONDS / 64, blk, 0, stream>>>(
            cur, bgraph, wt_hi, wt_lo, binput_h, nxt);
        __half* t = nxt; nxt = (__half*)cur; cur = t;
    }
    // final message in cur

    // atom_h = relu(concat(fatoms, gather6(fp16 msg)) @ W_o + b_o)
    gemm_fused<2><<<N_ATOMS / BM, blk, 0, stream>>>(
        fatoms, ATOM_FDIM, (const void*)cur, agraph, W_o, b_o, nullptr,
        atom_h, nullptr, ATOM_FDIM + HIDDEN);

    // q_all = atom_h @ W_a
    gemm_fused<3><<<N_ATOMS / BM, blk, 0, stream>>>(
        atom_h, HIDDEN, nullptr, nullptr, W_a, nullptr, nullptr,
        q_all, nullptr, HIDDEN);

    // per-molecule: logits, softmax, P = att@h, hsum
    attn_mid<<<N_MOLS, dim3(512), 0, stream>>>(atom_h, q_all, P_all, hsum);

    // out[mol] = (hsum + sum_rows relu(P @ W_b + b_b)) / 32
    gemm_fused<4><<<N_ATOMS / BM, blk, 0, stream>>>(
        P_all, HIDDEN, nullptr, nullptr, W_b, b_b, hsum,
        out, nullptr, HIDDEN);
}